// Round 1
// baseline (857.252 us; speedup 1.0000x reference)
//
#include <hip/hip_runtime.h>
#include <hip/hip_bf16.h>

typedef __attribute__((ext_vector_type(8))) short bf16x8;
typedef __attribute__((ext_vector_type(4))) float f32x4;
typedef __attribute__((ext_vector_type(4))) unsigned short u16x4;

#define BB 4
#define SS 2048
#define DD 2048
#define HH 16
#define HDD 128
// QK buffer: [B*S][4096] bf16 (Q cols 0..2047, K cols 2048..4095)
// Vt buffer: [B*H][128][2048] bf16 (V transposed: hd-major, s contiguous)

__device__ __forceinline__ unsigned short f2bf(float f) {
  __hip_bfloat16 b = __float2bfloat16(f);
  return *reinterpret_cast<unsigned short*>(&b);
}
__device__ __forceinline__ float bf2f(short u) {
  unsigned short t = (unsigned short)u;
  __hip_bfloat16 b = *reinterpret_cast<__hip_bfloat16*>(&t);
  return __bfloat162float(b);
}
__device__ __forceinline__ void gl_lds16(const void* g, void* l) {
  __builtin_amdgcn_global_load_lds((const __attribute__((address_space(1))) unsigned int*)g,
                                   (__attribute__((address_space(3))) unsigned int*)l, 16, 0, 0);
}

// ---------------- fp32 -> bf16 conversion (vectorized) ----------------
__global__ __launch_bounds__(256) void convertk(const float* __restrict__ src,
                                                __hip_bfloat16* __restrict__ dst, int n4) {
  int i = blockIdx.x * 256 + threadIdx.x;
  if (i >= n4) return;
  f32x4 v = ((const f32x4*)src)[i];
  u16x4 o;
  o[0] = f2bf(v[0]); o[1] = f2bf(v[1]); o[2] = f2bf(v[2]); o[3] = f2bf(v[3]);
  ((u16x4*)dst)[i] = o;
}

// ---------------- B^T GEMM: C[m][n] = sum_k A[m][k] * Bw[n][k] ----------------
// MODE 0: epilogue -> QK buffer (n<4096, ld 4096) or Vt (n>=4096, transposed), bf16
// MODE 1: epilogue -> float C row-major [M][N]
template <int MODE>
__global__ __launch_bounds__(256) void gemm_bt(const __hip_bfloat16* __restrict__ A,
                                               const __hip_bfloat16* __restrict__ Bw,
                                               __hip_bfloat16* __restrict__ Cbf,
                                               __hip_bfloat16* __restrict__ Vt,
                                               float* __restrict__ Cf,
                                               int M, int N, int K) {
  __shared__ __hip_bfloat16 As[128 * 32];
  __shared__ __hip_bfloat16 Bs[128 * 32];
  const int tid = threadIdx.x;
  const int wave = tid >> 6, lane = tid & 63;
  const int l15 = lane & 15, l4 = lane >> 4;
  const int bm = blockIdx.x, bn = blockIdx.y;
  const int wr = (wave >> 1) * 64, wc = (wave & 1) * 64;

  const long arow = (long)(bm * 128 + (tid >> 2)) * K + (tid & 3) * 8;
  const long brow = (long)(bn * 128 + (tid >> 2)) * K + (tid & 3) * 8;

  f32x4 acc[4][4] = {};

  for (int k0 = 0; k0 < K; k0 += 32) {
    const __hip_bfloat16* ga = A + arow + k0;
    const __hip_bfloat16* gb = Bw + brow + k0;
    gl_lds16(ga, As + tid * 8);
    gl_lds16(ga + (long)64 * K, As + 2048 + tid * 8);
    gl_lds16(gb, Bs + tid * 8);
    gl_lds16(gb + (long)64 * K, Bs + 2048 + tid * 8);
    __syncthreads();

    bf16x8 af[4], bg[4];
#pragma unroll
    for (int i = 0; i < 4; i++) {
      af[i] = *(const bf16x8*)(As + (wr + i * 16 + l15) * 32 + l4 * 8);
      bg[i] = *(const bf16x8*)(Bs + (wc + i * 16 + l15) * 32 + l4 * 8);
    }
#pragma unroll
    for (int mi = 0; mi < 4; mi++)
#pragma unroll
      for (int nj = 0; nj < 4; nj++)
        acc[mi][nj] = __builtin_amdgcn_mfma_f32_16x16x32_bf16(af[mi], bg[nj], acc[mi][nj], 0, 0, 0);
    __syncthreads();
  }

  if (MODE == 0) {
    if (bn * 128 < 4096) {
      // Q or K region -> QK buffer, ld = 4096
#pragma unroll
      for (int mi = 0; mi < 4; mi++)
#pragma unroll
        for (int nj = 0; nj < 4; nj++) {
          int n = bn * 128 + wc + nj * 16 + l15;
#pragma unroll
          for (int r = 0; r < 4; r++) {
            int m = bm * 128 + wr + mi * 16 + l4 * 4 + r;
            Cbf[(long)m * 4096 + n] = __float2bfloat16(acc[mi][nj][r]);
          }
        }
    } else {
      // V region -> Vt[(b*16+h)*128+hd][s], pack 4 consecutive s
#pragma unroll
      for (int mi = 0; mi < 4; mi++)
#pragma unroll
        for (int nj = 0; nj < 4; nj++) {
          int e = bn * 128 + wc + nj * 16 + l15 - 4096;
          int hh = e >> 7, hd = e & 127;
          int m0 = bm * 128 + wr + mi * 16 + l4 * 4;
          int b = m0 >> 11, s0 = m0 & (SS - 1);
          u16x4 pk;
#pragma unroll
          for (int r = 0; r < 4; r++) pk[r] = f2bf(acc[mi][nj][r]);
          *(u16x4*)(Vt + (((long)(b * HH + hh) * 128 + hd) * SS + s0)) = pk;
        }
    }
  } else {
#pragma unroll
    for (int mi = 0; mi < 4; mi++)
#pragma unroll
      for (int nj = 0; nj < 4; nj++) {
        int n = bn * 128 + wc + nj * 16 + l15;
#pragma unroll
        for (int r = 0; r < 4; r++) {
          int m = bm * 128 + wr + mi * 16 + l4 * 4 + r;
          Cf[(long)m * N + n] = acc[mi][nj][r];
        }
      }
  }
}

// ---------------- RoPE on Q and K (in place, bf16x8 = 4 pairs) ----------------
__global__ __launch_bounds__(256) void rope_k(__hip_bfloat16* __restrict__ qkbuf,
                                              const float* __restrict__ fc,
                                              const float* __restrict__ fs,
                                              const int* __restrict__ posp) {
  const int pos = *posp;
  int g = blockIdx.x * 256 + threadIdx.x;  // B*S*H*16 = 2,097,152
  int i4 = g & 15;
  int h = (g >> 4) & 15;
  int m = g >> 8;  // b*S + s
  int s = m & (SS - 1);
  long base = (long)m * 4096 + h * 128 + i4 * 8;
  bf16x8 q = *(bf16x8*)(qkbuf + base);
  bf16x8 k = *(bf16x8*)(qkbuf + base + 2048);
  f32x4 c = *(const f32x4*)(fc + (long)(pos + s) * 64 + i4 * 4);
  f32x4 sn = *(const f32x4*)(fs + (long)(pos + s) * 64 + i4 * 4);
  bf16x8 qo, ko;
#pragma unroll
  for (int j = 0; j < 4; j++) {
    float cj = c[j], sj = sn[j];
    float q0 = bf2f(q[2 * j]), q1 = bf2f(q[2 * j + 1]);
    float k0 = bf2f(k[2 * j]), k1 = bf2f(k[2 * j + 1]);
    qo[2 * j] = (short)f2bf(q0 * cj - q1 * sj);
    qo[2 * j + 1] = (short)f2bf(q0 * sj + q1 * cj);
    ko[2 * j] = (short)f2bf(k0 * cj - k1 * sj);
    ko[2 * j + 1] = (short)f2bf(k0 * sj + k1 * cj);
  }
  *(bf16x8*)(qkbuf + base) = qo;
  *(bf16x8*)(qkbuf + base + 2048) = ko;
}

// ---------------- causal flash attention ----------------
// grid (16 qblocks, 64 bh); 4 waves x 32 q-rows; KVBLK=64
__global__ __launch_bounds__(256) void attn_k(const __hip_bfloat16* __restrict__ qk,
                                              const __hip_bfloat16* __restrict__ vt,
                                              __hip_bfloat16* __restrict__ aout,
                                              const int* __restrict__ posp) {
  __shared__ __hip_bfloat16 Ks[64 * 128];   // [key][hd], XOR-swizzled
  __shared__ __hip_bfloat16 Vs[128 * 64];   // [hd][kv] (V^T), XOR-swizzled
  __shared__ __hip_bfloat16 Ps[4][32 * 64]; // per-wave P, XOR-swizzled
  const int pos = *posp;
  const int qb = blockIdx.x;  // 0..15
  const int bh = blockIdx.y;  // 0..63
  const int b = bh >> 4, h = bh & 15;
  const int tid = threadIdx.x;
  const int wave = tid >> 6, lane = tid & 63;
  const int l15 = lane & 15, l4 = lane >> 4;
  const int qwb = qb * 128 + wave * 32;

  // Q fragments in registers (rows = q, k = hd chunks of 32)
  bf16x8 qf[2][4];
#pragma unroll
  for (int mi = 0; mi < 2; mi++)
#pragma unroll
    for (int kk = 0; kk < 4; kk++) {
      long row = (long)b * SS + qwb + mi * 16 + l15;
      qf[mi][kk] = *(const bf16x8*)(qk + row * 4096 + h * 128 + kk * 32 + l4 * 8);
    }

  f32x4 accO[2][8] = {};
  float mrun[2][4], lrun[2][4];
#pragma unroll
  for (int mi = 0; mi < 2; mi++)
#pragma unroll
    for (int r = 0; r < 4; r++) { mrun[mi][r] = -1e30f; lrun[mi][r] = 0.f; }

  const int qmax = qb * 128 + 127;
  int ntiles = (pos + qmax) / 64 + 1;
  if (ntiles > SS / 64) ntiles = SS / 64;
  const float sc = 0.08838834764831845f;  // 1/sqrt(128)

  for (int t = 0; t < ntiles; ++t) {
    const int kv0 = t * 64;
    __syncthreads();
    // reg-stage K tile and V^T tile into swizzled LDS
    bf16x8 kreg[4], vreg[4];
#pragma unroll
    for (int i = 0; i < 4; i++) {
      int ch = i * 256 + tid;
      int kr = ch >> 4, kc = ch & 15;
      kreg[i] = *(const bf16x8*)(qk + ((long)b * SS + kv0 + kr) * 4096 + 2048 + h * 128 + kc * 8);
      int hd = ch >> 3, vc = ch & 7;
      vreg[i] = *(const bf16x8*)(vt + ((long)bh * 128 + hd) * SS + kv0 + vc * 8);
    }
#pragma unroll
    for (int i = 0; i < 4; i++) {
      int ch = i * 256 + tid;
      int kr = ch >> 4, kc = ch & 15;
      *(bf16x8*)(Ks + ((kr * 128 + kc * 8) ^ ((kr & 7) << 3))) = kreg[i];
      int hd = ch >> 3, vc = ch & 7;
      *(bf16x8*)(Vs + ((hd * 64 + vc * 8) ^ ((hd & 7) << 3))) = vreg[i];
    }
    __syncthreads();

    // S = Q K^T  (S frag: col=key=l15, row=q=l4*4+r)
    f32x4 sfr[2][4] = {};
#pragma unroll
    for (int ni = 0; ni < 4; ni++) {
      const int key = ni * 16 + l15;
      const int sw = (key & 7) << 3;
      bf16x8 kf[4];
#pragma unroll
      for (int kk = 0; kk < 4; kk++)
        kf[kk] = *(const bf16x8*)(Ks + ((key * 128 + kk * 32 + l4 * 8) ^ sw));
#pragma unroll
      for (int mi = 0; mi < 2; mi++)
#pragma unroll
        for (int kk = 0; kk < 4; kk++)
          sfr[mi][ni] = __builtin_amdgcn_mfma_f32_16x16x32_bf16(qf[mi][kk], kf[kk], sfr[mi][ni], 0, 0, 0);
    }

    // scale + causal mask
    const bool needmask = (kv0 + 63) > (pos + qb * 128);
#pragma unroll
    for (int mi = 0; mi < 2; mi++)
#pragma unroll
      for (int ni = 0; ni < 4; ni++)
#pragma unroll
        for (int r = 0; r < 4; r++) {
          float v = sfr[mi][ni][r] * sc;
          if (needmask) {
            int key = kv0 + ni * 16 + l15;
            int q = qwb + mi * 16 + l4 * 4 + r;
            if (key > pos + q) v = -1e30f;
          }
          sfr[mi][ni][r] = v;
        }

    // online softmax (row reduce over 16-lane groups)
#pragma unroll
    for (int mi = 0; mi < 2; mi++) {
      f32x4 mx = sfr[mi][0];
#pragma unroll
      for (int ni = 1; ni < 4; ni++)
#pragma unroll
        for (int r = 0; r < 4; r++) mx[r] = fmaxf(mx[r], sfr[mi][ni][r]);
#pragma unroll
      for (int d = 1; d < 16; d <<= 1)
#pragma unroll
        for (int r = 0; r < 4; r++) mx[r] = fmaxf(mx[r], __shfl_xor(mx[r], d, 64));
      float mnew[4], scal[4];
#pragma unroll
      for (int r = 0; r < 4; r++) {
        mnew[r] = fmaxf(mrun[mi][r], mx[r]);
        scal[r] = __expf(mrun[mi][r] - mnew[r]);
        mrun[mi][r] = mnew[r];
      }
      f32x4 rs = {0.f, 0.f, 0.f, 0.f};
#pragma unroll
      for (int ni = 0; ni < 4; ni++)
#pragma unroll
        for (int r = 0; r < 4; r++) {
          float p = __expf(sfr[mi][ni][r] - mnew[r]);
          rs[r] += p;
          int prow = mi * 16 + l4 * 4 + r;
          Ps[wave][(prow * 64 + ni * 16 + l15) ^ ((prow & 7) << 3)] = __float2bfloat16(p);
        }
#pragma unroll
      for (int d = 1; d < 16; d <<= 1)
#pragma unroll
        for (int r = 0; r < 4; r++) rs[r] += __shfl_xor(rs[r], d, 64);
#pragma unroll
      for (int r = 0; r < 4; r++) lrun[mi][r] = lrun[mi][r] * scal[r] + rs[r];
#pragma unroll
      for (int ni = 0; ni < 8; ni++)
#pragma unroll
        for (int r = 0; r < 4; r++) accO[mi][ni][r] *= scal[r];
    }

    // O += P * V   (A = P rows, B = V via V^T rows)
#pragma unroll
    for (int kk = 0; kk < 2; kk++) {
      bf16x8 pf[2];
#pragma unroll
      for (int mi = 0; mi < 2; mi++) {
        int prow = mi * 16 + l15;
        pf[mi] = *(const bf16x8*)(Ps[wave] + ((prow * 64 + kk * 32 + l4 * 8) ^ ((prow & 7) << 3)));
      }
#pragma unroll
      for (int ni = 0; ni < 8; ni++) {
        int hd = ni * 16 + l15;
        bf16x8 vf = *(const bf16x8*)(Vs + ((hd * 64 + kk * 32 + l4 * 8) ^ ((hd & 7) << 3)));
#pragma unroll
        for (int mi = 0; mi < 2; mi++)
          accO[mi][ni] = __builtin_amdgcn_mfma_f32_16x16x32_bf16(pf[mi], vf, accO[mi][ni], 0, 0, 0);
      }
    }
  }

  // epilogue: normalize and store bf16
#pragma unroll
  for (int mi = 0; mi < 2; mi++) {
    float inv[4];
#pragma unroll
    for (int r = 0; r < 4; r++) inv[r] = 1.0f / lrun[mi][r];
#pragma unroll
    for (int ni = 0; ni < 8; ni++)
#pragma unroll
      for (int r = 0; r < 4; r++) {
        int q = qwb + mi * 16 + l4 * 4 + r;
        int hd = ni * 16 + l15;
        aout[((long)b * SS + q) * 2048 + h * 128 + hd] = __float2bfloat16(accO[mi][ni][r] * inv[r]);
      }
  }
}

extern "C" void kernel_launch(void* const* d_in, const int* in_sizes, int n_in,
                              void* d_out, int out_size, void* d_ws, size_t ws_size,
                              hipStream_t stream) {
  (void)in_sizes; (void)n_in; (void)out_size; (void)ws_size;
  const float* h  = (const float*)d_in[0];
  const float* Wq = (const float*)d_in[1];
  const float* Wk = (const float*)d_in[2];
  const float* Wv = (const float*)d_in[3];
  const float* Wo = (const float*)d_in[4];
  const float* fc = (const float*)d_in[7];
  const float* fs = (const float*)d_in[8];
  const int* pos  = (const int*)d_in[9];
  float* out = (float*)d_out;

  char* ws = (char*)d_ws;
  __hip_bfloat16* hb    = (__hip_bfloat16*)(ws);                 // 33,554,432 B
  __hip_bfloat16* wqkv  = (__hip_bfloat16*)(ws + 33554432);      // 25,165,824 B
  __hip_bfloat16* wo_b  = (__hip_bfloat16*)(ws + 58720256);      //  8,388,608 B
  __hip_bfloat16* qkbuf = (__hip_bfloat16*)(ws + 67108864);      // 67,108,864 B
  __hip_bfloat16* vt    = (__hip_bfloat16*)(ws + 134217728);     // 33,554,432 B
  __hip_bfloat16* aout  = hb;  // alias: hb dead after GEMM1     // total 167,772,160 B

  // fp32 -> bf16
  convertk<<<16384, 256, 0, stream>>>(h, hb, 4194304);
  convertk<<<4096, 256, 0, stream>>>(Wq, wqkv, 1048576);
  convertk<<<4096, 256, 0, stream>>>(Wk, wqkv + 4194304, 1048576);
  convertk<<<4096, 256, 0, stream>>>(Wv, wqkv + 8388608, 1048576);
  convertk<<<4096, 256, 0, stream>>>(Wo, wo_b, 1048576);

  // QKV projection: M=8192, N=6144, K=2048
  gemm_bt<0><<<dim3(64, 48), 256, 0, stream>>>(hb, wqkv, qkbuf, vt, nullptr, 8192, 6144, 2048);

  // RoPE on Q,K
  rope_k<<<8192, 256, 0, stream>>>(qkbuf, fc, fs, pos);

  // causal flash attention
  attn_k<<<dim3(16, 64), 256, 0, stream>>>(qkbuf, vt, aout, pos);

  // output projection: M=8192, N=2048, K=2048 -> fp32 d_out
  gemm_bt<1><<<dim3(64, 16), 256, 0, stream>>>(aout, wo_b, nullptr, nullptr, out, 8192, 2048, 2048);
}